// Round 1
// baseline (240.137 us; speedup 1.0000x reference)
//
#include <hip/hip_runtime.h>

#define LSEQ 200
#define KCAP 4
#define NVOC 100000

// ---------------------------------------------------------------------------
// Kernel 1: P = (E with row 0 zeroed) @ S, P: (NVOC, 64) in workspace.
// 16 vocab rows per block; thread computes 4 rows x 1 col via transposed
// E-tile in LDS (float4 broadcast) + S in LDS.
// ---------------------------------------------------------------------------
__global__ __launch_bounds__(256) void precompute_P(
    const float* __restrict__ E, const float* __restrict__ S,
    float* __restrict__ P)
{
    __shared__ __align__(16) float Sl[64 * 64];
    __shared__ __align__(16) float Et[64 * 16];   // Et[e*16 + r] = E[(vbase+r)*64 + e]
    const int tid = threadIdx.x;
    #pragma unroll
    for (int t = tid; t < 4096; t += 256) Sl[t] = S[t];
    const int vbase = blockIdx.x * 16;
    #pragma unroll
    for (int t = tid; t < 1024; t += 256) {
        int r = t >> 6, e = t & 63;
        Et[e * 16 + r] = E[(vbase + r) * 64 + e];
    }
    __syncthreads();
    const int d = tid & 63, q = tid >> 6;
    float a0 = 0.f, a1 = 0.f, a2 = 0.f, a3 = 0.f;
    #pragma unroll
    for (int e = 0; e < 64; e++) {
        float4 ev = *(const float4*)(Et + e * 16 + q * 4);  // broadcast b128
        float  s  = Sl[e * 64 + d];                          // 2-way bank: free
        a0 = fmaf(ev.x, s, a0);
        a1 = fmaf(ev.y, s, a1);
        a2 = fmaf(ev.z, s, a2);
        a3 = fmaf(ev.w, s, a3);
    }
    const int v0 = vbase + q * 4;
    if (v0 == 0) a0 = 0.f;               // padding_idx=0 -> P row 0 is zero
    P[(v0 + 0) * 64 + d] = a0;
    P[(v0 + 1) * 64 + d] = a1;
    P[(v0 + 2) * 64 + d] = a2;
    P[(v0 + 3) * 64 + d] = a3;
}

// ---------------------------------------------------------------------------
// Kernel 2: one batch row per block (256 threads = 4 waves).
//   hisP row-block in registers (wave = 50 l's, lane = d) for the caps einsum;
//   LDS copy at stride 65 (conflict-free for both d-lanes and l-lanes) for
//   the B-update einsum. All small shared vectors read as float4 broadcasts.
// ---------------------------------------------------------------------------
__global__ __launch_bounds__(256, 2) void mind_row(
    const int*   __restrict__ his, const float* __restrict__ P,
    const float* __restrict__ B0,  const float* __restrict__ W1,
    const float* __restrict__ b1,  const float* __restrict__ W2,
    const float* __restrict__ b2,  float* __restrict__ out)
{
    __shared__ __align__(16) float hisPl[LSEQ * 65];   // 52000 B; reused as h4 in MLP
    __shared__ __align__(16) float W4[LSEQ * 4];       // W4[l*4+k]
    __shared__ __align__(16) float Bm[KCAP * LSEQ];    // Bm[k*200+l]
    __shared__ __align__(16) float caps4[64 * 4];      // caps4[d*4+k]
    __shared__ __align__(16) float part[4 * 4 * 64];   // part[q*256 + k*64 + d]
    __shared__ float bigneg[LSEQ];
    __shared__ int   idxs[LSEQ];

    const int b    = blockIdx.x;
    const int tid  = threadIdx.x;
    const int lane = tid & 63;
    const int wv   = tid >> 6;

    for (int l = tid; l < LSEQ; l += 256) {
        int id = his[b * LSEQ + l];
        idxs[l]   = id;
        bigneg[l] = (id != 0) ? 0.f : -1e30f;
    }
    for (int t = tid; t < KCAP * LSEQ; t += 256) Bm[t] = B0[t];
    __syncthreads();

    // Gather: thread covers l in [wv*50, wv*50+50), column d = lane.
    float hp[50];
    #pragma unroll
    for (int i = 0; i < 50; i++) {
        int l = wv * 50 + i;
        float v = P[idxs[l] * 64 + lane];     // 256B coalesced per wave
        hp[i] = v;
        hisPl[l * 65 + lane] = v;             // (l+d)%32 banks: conflict-free
    }
    __syncthreads();

    for (int r = 0; r < 3; r++) {
        // A: masked softmax over l, capsule k = wv (one wave per capsule)
        {
            const float* Bk = Bm + wv * LSEQ;
            float x0 = Bk[lane]       + bigneg[lane];
            float x1 = Bk[lane + 64]  + bigneg[lane + 64];
            float x2 = Bk[lane + 128] + bigneg[lane + 128];
            float x3 = (lane < 8) ? (Bk[lane + 192] + bigneg[lane + 192]) : -3.0e38f;
            float m = fmaxf(fmaxf(x0, x1), fmaxf(x2, x3));
            #pragma unroll
            for (int off = 32; off; off >>= 1) m = fmaxf(m, __shfl_xor(m, off, 64));
            float e0 = __expf(x0 - m), e1 = __expf(x1 - m), e2 = __expf(x2 - m);
            float e3 = (lane < 8) ? __expf(x3 - m) : 0.f;
            float s = e0 + e1 + e2 + e3;
            #pragma unroll
            for (int off = 32; off; off >>= 1) s += __shfl_xor(s, off, 64);
            float inv = 1.f / s;
            W4[lane * 4 + wv]         = e0 * inv;
            W4[(lane + 64) * 4 + wv]  = e1 * inv;
            W4[(lane + 128) * 4 + wv] = e2 * inv;
            if (lane < 8) W4[(lane + 192) * 4 + wv] = e3 * inv;
        }
        __syncthreads();

        // B: caps partials from register-resident hisP (LDS: broadcasts only)
        {
            float a0 = 0, a1 = 0, a2 = 0, a3 = 0;
            #pragma unroll
            for (int i = 0; i < 50; i++) {
                int l = wv * 50 + i;
                float4 w = *(const float4*)(W4 + l * 4);   // broadcast b128
                float  v = hp[i];
                a0 = fmaf(w.x, v, a0);
                a1 = fmaf(w.y, v, a1);
                a2 = fmaf(w.z, v, a2);
                a3 = fmaf(w.w, v, a3);
            }
            part[wv * 256 + lane]       = a0;
            part[wv * 256 + 64 + lane]  = a1;
            part[wv * 256 + 128 + lane] = a2;
            part[wv * 256 + 192 + lane] = a3;
        }
        __syncthreads();

        // C: reduce partials + squash; thread = (k = wv, d = lane)
        {
            float c = part[wv * 64 + lane]       + part[256 + wv * 64 + lane]
                    + part[512 + wv * 64 + lane] + part[768 + wv * 64 + lane];
            float n2 = c * c;
            #pragma unroll
            for (int off = 32; off; off >>= 1) n2 += __shfl_xor(n2, off, 64);
            float n  = sqrtf(n2);
            float sc = n2 / ((1.f + n2) * n + 1e-9f);
            c *= sc;
            caps4[lane * 4 + wv] = c;
        }
        __syncthreads();

        if (r < 2) {
            // D: B[k][l] += caps[k] . hisP[l]  (thread per l; stride-65 = no conflicts)
            if (tid < LSEQ) {
                const int l = tid;
                float d0 = 0, d1 = 0, d2 = 0, d3 = 0;
                #pragma unroll 8
                for (int d = 0; d < 64; d++) {
                    float  v = hisPl[l * 65 + d];
                    float4 c = *(const float4*)(caps4 + d * 4);  // broadcast b128
                    d0 = fmaf(c.x, v, d0);
                    d1 = fmaf(c.y, v, d1);
                    d2 = fmaf(c.z, v, d2);
                    d3 = fmaf(c.w, v, d3);
                }
                Bm[l]       += d0;
                Bm[200 + l] += d1;
                Bm[400 + l] += d2;
                Bm[600 + l] += d3;
            }
            __syncthreads();
        }
    }

    // MLP. hisP is dead -> reuse its LDS for h4[f*4+k].
    float* h4 = hisPl;
    {
        const int f = tid;
        float h0 = 0, h1 = 0, h2 = 0, h3 = 0;
        #pragma unroll 8
        for (int d = 0; d < 64; d++) {
            float  w = W1[d * 256 + f];                      // 256B coalesced, L2-hot
            float4 c = *(const float4*)(caps4 + d * 4);
            h0 = fmaf(c.x, w, h0);
            h1 = fmaf(c.y, w, h1);
            h2 = fmaf(c.z, w, h2);
            h3 = fmaf(c.w, w, h3);
        }
        float bb = b1[f];
        h0 = fmaxf(h0 + bb, 0.f);
        h1 = fmaxf(h1 + bb, 0.f);
        h2 = fmaxf(h2 + bb, 0.f);
        h3 = fmaxf(h3 + bb, 0.f);
        h4[f * 4 + 0] = h0; h4[f * 4 + 1] = h1;
        h4[f * 4 + 2] = h2; h4[f * 4 + 3] = h3;
    }
    __syncthreads();
    {
        // out partials: q = wv covers f in [q*64, q*64+64), d = lane
        float o0 = 0, o1 = 0, o2 = 0, o3 = 0;
        #pragma unroll 8
        for (int i = 0; i < 64; i++) {
            int f = wv * 64 + i;
            float  w  = W2[f * 64 + lane];                   // 256B coalesced, L2-hot
            float4 hv = *(const float4*)(h4 + f * 4);        // broadcast b128
            o0 = fmaf(hv.x, w, o0);
            o1 = fmaf(hv.y, w, o1);
            o2 = fmaf(hv.z, w, o2);
            o3 = fmaf(hv.w, w, o3);
        }
        part[wv * 256 + lane]       = o0;
        part[wv * 256 + 64 + lane]  = o1;
        part[wv * 256 + 128 + lane] = o2;
        part[wv * 256 + 192 + lane] = o3;
    }
    __syncthreads();
    {
        float o = part[wv * 64 + lane]       + part[256 + wv * 64 + lane]
                + part[512 + wv * 64 + lane] + part[768 + wv * 64 + lane];
        out[b * 256 + tid] = o + b2[lane];   // (b, k=wv, d=lane) contiguous
    }
}

extern "C" void kernel_launch(void* const* d_in, const int* in_sizes, int n_in,
                              void* d_out, int out_size, void* d_ws, size_t ws_size,
                              hipStream_t stream) {
    const int*   his = (const int*)  d_in[0];
    const float* E   = (const float*)d_in[1];
    const float* S   = (const float*)d_in[2];
    const float* B0  = (const float*)d_in[3];
    const float* W1  = (const float*)d_in[4];
    const float* b1  = (const float*)d_in[5];
    const float* W2  = (const float*)d_in[6];
    const float* b2  = (const float*)d_in[7];
    float* out = (float*)d_out;
    float* P   = (float*)d_ws;            // NVOC*64 floats = 25.6 MB scratch

    precompute_P<<<NVOC / 16, 256, 0, stream>>>(E, S, P);
    mind_row<<<4096, 256, 0, stream>>>(his, P, B0, W1, b1, W2, b2, out);
}